// Round 6
// baseline (706.359 us; speedup 1.0000x reference)
//
#include <hip/hip_runtime.h>
#include <hip/hip_bf16.h>
#include <math.h>

#define LN 4
#define B_ 8
#define D_ 2048
#define DI 4096
#define N_ 128
#define H_ 64
#define P_ 64
#define K_ 4
#define M_ 8
#define V_ 50288
#define CCH (DI + 2*N_)           // 4352
#define DOUT (2*DI + 2*N_ + H_)   // 8512
#define EPSF 1e-5f

typedef float f32x4 __attribute__((ext_vector_type(4)));

__device__ inline float wave_sum(float v) {
  #pragma unroll
  for (int off = 32; off > 0; off >>= 1) v += __shfl_xor(v, off, 64);
  return v;
}

// Fold-reduce 8 per-lane accumulators: returns, in lane l, the full 64-lane
// sum of a[l&7].  (HW-verified rounds 2-5.)
__device__ inline float fold_reduce8(const float a[8], int lane) {
  float t0[4];
  #pragma unroll
  for (int r = 0; r < 4; ++r) {
    float keep = (lane & 1) ? a[2*r+1] : a[2*r];
    float send = (lane & 1) ? a[2*r]   : a[2*r+1];
    t0[r] = keep + __shfl_xor(send, 1, 64);
  }
  float t1[2];
  #pragma unroll
  for (int r = 0; r < 2; ++r) {
    float keep = (lane & 2) ? t0[2*r+1] : t0[2*r];
    float send = (lane & 2) ? t0[2*r]   : t0[2*r+1];
    t1[r] = keep + __shfl_xor(send, 2, 64);
  }
  float keep = (lane & 4) ? t1[1] : t1[0];
  float send = (lane & 4) ? t1[0] : t1[1];
  float u = keep + __shfl_xor(send, 4, 64);
  u += __shfl_xor(u, 8, 64);
  u += __shfl_xor(u, 16, 64);
  u += __shfl_xor(u, 32, 64);
  return u;
}

// ------- rmsnorm (one block per batch row), with optional fused embed-gather,
// ------- residual init, and zx zeroing
__global__ __launch_bounds__(256)
void k_rmsnorm(const float* __restrict__ in, const float* __restrict__ w,
               float* __restrict__ out, const int* __restrict__ ids,
               const float* __restrict__ emb, float* __restrict__ res_out,
               float* __restrict__ zbuf) {
  __shared__ float lds[4];
  int b = blockIdx.x, tid = threadIdx.x;
  const float* row = ids ? (emb + (size_t)ids[b] * D_) : (in + (size_t)b * D_);
  f32x4 v0 = *reinterpret_cast<const f32x4*>(row + tid * 8);
  f32x4 v1 = *reinterpret_cast<const f32x4*>(row + tid * 8 + 4);
  if (res_out) {
    *reinterpret_cast<f32x4*>(res_out + (size_t)b * D_ + tid * 8)     = v0;
    *reinterpret_cast<f32x4*>(res_out + (size_t)b * D_ + tid * 8 + 4) = v1;
  }
  if (zbuf) {   // zero this batch-row of zx before in_proj atomics
    f32x4* z4 = reinterpret_cast<f32x4*>(zbuf + (size_t)b * DOUT);
    for (int i = tid; i < DOUT / 4; i += 256) z4[i] = (f32x4)0.f;
  }
  float ss = v0[0]*v0[0] + v0[1]*v0[1] + v0[2]*v0[2] + v0[3]*v0[3]
           + v1[0]*v1[0] + v1[1]*v1[1] + v1[2]*v1[2] + v1[3]*v1[3];
  float wsum = wave_sum(ss);
  int lane = tid & 63, wid = tid >> 6;
  if (lane == 0) lds[wid] = wsum;
  __syncthreads();
  float tot = lds[0] + lds[1] + lds[2] + lds[3];
  float scale = rsqrtf(tot / (float)D_ + EPSF);
  f32x4 w0 = *reinterpret_cast<const f32x4*>(w + tid * 8);
  f32x4 w1 = *reinterpret_cast<const f32x4*>(w + tid * 8 + 4);
  f32x4 o0 = v0 * scale * w0, o1 = v1 * scale * w1;
  *reinterpret_cast<f32x4*>(out + (size_t)b * D_ + tid * 8)     = o0;
  *reinterpret_cast<f32x4*>(out + (size_t)b * D_ + tid * 8 + 4) = o1;
}

// ---------------- in_proj: (8x2048)@(2048x8512), split-K(64) with atomics ----
// grid = 9 j-tiles * 64 k-tiles = 576 blocks (smoother tail than 288)
__global__ void k_inproj(const float* __restrict__ xn, const float* __restrict__ W,
                         float* __restrict__ zx) {
  __shared__ float xs[8][32];
  int jt = blockIdx.x % 9, kt = blockIdx.x / 9;
  int k0 = kt * 32;
  for (int i = threadIdx.x; i < 8 * 32; i += 256) {
    int r = i >> 5, kk = i & 31;
    xs[r][kk] = xn[r * D_ + k0 + kk];
  }
  __syncthreads();
  int j = jt * 1024 + threadIdx.x * 4;
  if (j >= DOUT) return;
  f32x4 acc[8];
  #pragma unroll
  for (int r = 0; r < 8; ++r) acc[r] = (f32x4)0.f;
  const float* Wp = W + (size_t)k0 * DOUT + j;
  for (int kk = 0; kk < 32; ++kk) {
    f32x4 w4 = __builtin_nontemporal_load(
        reinterpret_cast<const f32x4*>(Wp + (size_t)kk * DOUT));
    #pragma unroll
    for (int r = 0; r < 8; ++r) acc[r] += w4 * xs[r][kk];
  }
  #pragma unroll
  for (int r = 0; r < 8; ++r) {
    atomicAdd(&zx[r * DOUT + j + 0], acc[r][0]);
    atomicAdd(&zx[r * DOUT + j + 1], acc[r][1]);
    atomicAdd(&zx[r * DOUT + j + 2], acc[r][2]);
    atomicAdd(&zx[r * DOUT + j + 3], acc[r][3]);
  }
}

// ---------------- conv step + dt/dA + softmax(W_mc) --------------------------
__global__ void k_conv_dt(const float* __restrict__ zx, const float* __restrict__ conv_state,
                          const float* __restrict__ conv_w, const float* __restrict__ conv_b,
                          const float* __restrict__ A_log, const float* __restrict__ dt_bias,
                          const float* __restrict__ W_mc,
                          float* __restrict__ xbc, float* __restrict__ dts,
                          float* __restrict__ dav, float* __restrict__ wmc) {
  int gid = blockIdx.x * 256 + threadIdx.x;
  if (gid < B_ * CCH) {
    int b = gid / CCH, c = gid % CCH;
    f32x4 cs4 = *reinterpret_cast<const f32x4*>(conv_state + ((size_t)b * CCH + c) * K_);
    f32x4 cw4 = *reinterpret_cast<const f32x4*>(conv_w + (size_t)c * K_);
    float xnew = zx[b * DOUT + DI + c];
    float v = cs4[1] * cw4[0] + cs4[2] * cw4[1] + cs4[3] * cw4[2] + xnew * cw4[3] + conv_b[c];
    xbc[gid] = v / (1.f + expf(-v));   // silu
  }
  if (gid < B_ * H_) {
    int b = gid >> 6, h = gid & 63;
    float x = zx[b * DOUT + DI + CCH + h] + dt_bias[h];
    float sp = (x > 20.f) ? x : log1pf(expf(x));   // softplus
    dts[gid] = sp;
    dav[gid] = expf(-expf(A_log[h]) * sp);
  }
  if (gid == 0) {
    float mx = -1e30f;
    for (int i = 0; i < M_ + 1; ++i) mx = fmaxf(mx, W_mc[i]);
    float e[M_ + 1], s = 0.f;
    for (int i = 0; i < M_ + 1; ++i) { e[i] = expf(W_mc[i] - mx); s += e[i]; }
    for (int i = 0; i < M_ + 1; ++i) wmc[i] = e[i] / s;
  }
}

// ---------------- state update + MC fuse + y -------------------------------
__global__ __launch_bounds__(256)
void k_state(const float* __restrict__ xbc, const float* __restrict__ dts,
             const float* __restrict__ dav, const float* __restrict__ Dp_,
             const float* __restrict__ wmc, const float* __restrict__ ssm,
             const float* __restrict__ cached, float* __restrict__ y) {
  int wg = blockIdx.x * 4 + (threadIdx.x >> 6);   // [0, 16384)
  int lane = threadIdx.x & 63;
  int b = wg >> 11;
  int h = (wg >> 5) & 63;
  int pp = wg & 31;
  int hf = lane >> 5, il = lane & 31;
  int p = pp * 2 + hf;
  float xv  = xbc[b * CCH + h * 64 + p];
  float dtv = dts[b * 64 + h];
  float da  = dav[b * 64 + h];
  float w8  = wmc[8];
  const f32x4* xb4 = reinterpret_cast<const f32x4*>(xbc);
  f32x4 B4 = xb4[b * (CCH / 4) + DI / 4 + il];
  f32x4 C4 = xb4[b * (CCH / 4) + DI / 4 + N_ / 4 + il];
  const f32x4* sp4 = reinterpret_cast<const f32x4*>(ssm) +
                     ((size_t)((b * H_ + h) * P_ + p)) * (N_ / 4) + il;
  const f32x4* cp4 = reinterpret_cast<const f32x4*>(cached) +
                     ((size_t)(((b * M_) * H_ + h) * P_ + p)) * (N_ / 4) + il;
  f32x4 s4 = __builtin_nontemporal_load(sp4);
  f32x4 f4 = (s4 * da + B4 * (dtv * xv)) * w8;
  #pragma unroll
  for (int m = 0; m < 8; ++m) {
    f32x4 c4 = __builtin_nontemporal_load(cp4 + (size_t)m * (H_ * P_ * N_ / 4));
    f4 += c4 * wmc[m];
  }
  f4 *= C4;
  float acc = f4[0] + f4[1] + f4[2] + f4[3];
  #pragma unroll
  for (int off = 1; off < 32; off <<= 1) acc += __shfl_xor(acc, off, 64);
  if (il == 0) y[b * DI + h * 64 + p] = acc + Dp_[h] * xv;
}

// ---------------- gated RMS norm: y*silu(z) then rms over 4096 ---------------
__global__ void k_gatednorm(const float* __restrict__ y, const float* __restrict__ zx,
                            const float* __restrict__ mnw, float* __restrict__ yg) {
  __shared__ float lds[8];
  int b = blockIdx.x;
  float tv[16];
  float ss = 0.f;
  #pragma unroll
  for (int t = 0; t < 16; ++t) {
    int i = threadIdx.x + t * 256;
    float z = zx[b * DOUT + i];
    float v = y[b * DI + i] * (z / (1.f + expf(-z)));
    tv[t] = v; ss += v * v;
  }
  float wsum = wave_sum(ss);
  int lane = threadIdx.x & 63, wid = threadIdx.x >> 6;
  if (lane == 0) lds[wid] = wsum;
  __syncthreads();
  float tot = lds[0] + lds[1] + lds[2] + lds[3];
  float scale = rsqrtf(tot / (float)DI + EPSF);
  #pragma unroll
  for (int t = 0; t < 16; ++t) {
    int i = threadIdx.x + t * 256;
    yg[b * DI + i] = tv[t] * scale * mnw[i];
  }
}

// ---------------- out_proj: (8x4096)@(4096x2048) += res, split-K -------------
__global__ void k_outproj(const float* __restrict__ yg, const float* __restrict__ W,
                          float* __restrict__ res) {
  __shared__ float xs[8][32];
  int jt = blockIdx.x & 1, kt = blockIdx.x >> 1;
  int k0 = kt * 32;
  for (int i = threadIdx.x; i < 8 * 32; i += 256) {
    int r = i >> 5, kk = i & 31;
    xs[r][kk] = yg[r * DI + k0 + kk];
  }
  __syncthreads();
  int j = jt * 1024 + threadIdx.x * 4;
  f32x4 acc[8];
  #pragma unroll
  for (int r = 0; r < 8; ++r) acc[r] = (f32x4)0.f;
  const float* Wp = W + (size_t)k0 * D_ + j;
  for (int kk = 0; kk < 32; ++kk) {
    f32x4 w4 = __builtin_nontemporal_load(
        reinterpret_cast<const f32x4*>(Wp + (size_t)kk * D_));
    #pragma unroll
    for (int r = 0; r < 8; ++r) acc[r] += w4 * xs[r][kk];
  }
  #pragma unroll
  for (int r = 0; r < 8; ++r) {
    atomicAdd(&res[r * D_ + j + 0], acc[r][0]);
    atomicAdd(&res[r * D_ + j + 1], acc[r][1]);
    atomicAdd(&res[r * D_ + j + 2], acc[r][2]);
    atomicAdd(&res[r * D_ + j + 3], acc[r][3]);
  }
}

// ---------------- logits: full-D, 512 threads, wave-per-row-pair, no atomics -
// 64KB xs tile shared by 8 waves -> 2 blocks/CU = 16 waves/CU. Loads consumed
// in-loop (no preload arrays -> no spill). Direct stores, out written exactly
// once -> no zeroing pass, no atomics.
#define LGRID 1572   // 1572*8 waves = 12576; x2 row-pairs covers 25144 pairs
__global__ __launch_bounds__(512)
void k_logits(const float* __restrict__ xn, const float* __restrict__ emb,
              float* __restrict__ out) {
  __shared__ f32x4 xs[8][512];   // 64 KB = full (8,2048) xn
  const f32x4* xn4 = reinterpret_cast<const f32x4*>(xn);
  for (int i = threadIdx.x; i < 4096; i += 512)
    xs[i >> 9][i & 511] = xn4[i];
  __syncthreads();
  int wid = threadIdx.x >> 6, lane = threadIdx.x & 63;
  int gw = blockIdx.x * 8 + wid;
  const f32x4* e4 = reinterpret_cast<const f32x4*>(emb);
  for (int pi = gw; pi < V_ / 2; pi += LGRID * 8) {
    int v0 = pi * 2;
    const f32x4* e0 = e4 + (size_t)v0 * (D_ / 4);
    float acc0[8] = {0,0,0,0,0,0,0,0};
    float acc1[8] = {0,0,0,0,0,0,0,0};
    #pragma unroll 2
    for (int st = 0; st < 8; ++st) {
      int c = st * 64 + lane;
      f32x4 a = __builtin_nontemporal_load(e0 + c);
      f32x4 b = __builtin_nontemporal_load(e0 + (D_ / 4) + c);
      #pragma unroll
      for (int r = 0; r < 8; ++r) {
        f32x4 x = xs[r][c];
        acc0[r] += a[0]*x[0] + a[1]*x[1] + a[2]*x[2] + a[3]*x[3];
        acc1[r] += b[0]*x[0] + b[1]*x[1] + b[2]*x[2] + b[3]*x[3];
      }
    }
    float u0 = fold_reduce8(acc0, lane);
    float u1 = fold_reduce8(acc1, lane);
    if (lane < 8) {
      out[(size_t)lane * V_ + v0]     = u0;
      out[(size_t)lane * V_ + v0 + 1] = u1;
    }
  }
}

extern "C" void kernel_launch(void* const* d_in, const int* in_sizes, int n_in,
                              void* d_out, int out_size, void* d_ws, size_t ws_size,
                              hipStream_t stream) {
  const int*   ids    = (const int*)  d_in[0];
  const float* emb    = (const float*)d_in[1];
  const float* inW    = (const float*)d_in[2];
  const float* convW  = (const float*)d_in[3];
  const float* convB  = (const float*)d_in[4];
  const float* Alog   = (const float*)d_in[5];
  const float* dtB    = (const float*)d_in[6];
  const float* Dpar   = (const float*)d_in[7];
  const float* mnw    = (const float*)d_in[8];
  const float* outW   = (const float*)d_in[9];
  const float* lnw    = (const float*)d_in[10];
  const float* nfw    = (const float*)d_in[11];
  const float* Wmc    = (const float*)d_in[12];
  const float* convS  = (const float*)d_in[13];
  const float* ssmS   = (const float*)d_in[14];
  const float* cached = (const float*)d_in[15];
  float* out = (float*)d_out;
  float* ws  = (float*)d_ws;

  float* res = ws;            // 16384 floats
  float* xn  = ws + 16384;    // 16384
  float* zx  = ws + 32768;    // 68096
  float* xbc = ws + 100864;   // 34816
  float* dts = ws + 135680;   // 512
  float* dav = ws + 136192;   // 512
  float* wmc = ws + 136704;   // 64
  float* y   = ws + 136768;   // 32768
  float* yg  = ws + 169536;   // 32768

  for (int l = 0; l < LN; ++l) {
    if (l == 0)
      k_rmsnorm<<<8, 256, 0, stream>>>(nullptr, lnw, xn, ids, emb, res, zx);
    else
      k_rmsnorm<<<8, 256, 0, stream>>>(res, lnw + (size_t)l * D_, xn,
                                       nullptr, nullptr, nullptr, zx);
    k_inproj<<<576, 256, 0, stream>>>(xn, inW + (size_t)l * D_ * DOUT, zx);
    k_conv_dt<<<136, 256, 0, stream>>>(zx,
        convS + (size_t)l * B_ * CCH * K_, convW + (size_t)l * CCH * K_,
        convB + (size_t)l * CCH, Alog + l * H_, dtB + l * H_, Wmc + l * (M_ + 1),
        xbc, dts, dav, wmc);
    k_state<<<4096, 256, 0, stream>>>(xbc, dts, dav, Dpar + l * H_, wmc,
        ssmS + (size_t)l * B_ * H_ * P_ * N_,
        cached + (size_t)l * B_ * M_ * H_ * P_ * N_, y);
    k_gatednorm<<<8, 256, 0, stream>>>(y, zx, mnw + (size_t)l * DI, yg);
    k_outproj<<<256, 256, 0, stream>>>(yg, outW + (size_t)l * DI * D_, res);
  }
  k_rmsnorm<<<8, 256, 0, stream>>>(res, nfw, xn, nullptr, nullptr, nullptr, nullptr);
  k_logits<<<LGRID, 512, 0, stream>>>(xn, emb, out);
}

// Round 7
// 477.670 us; speedup vs baseline: 1.4788x; 1.4788x over previous
//
#include <hip/hip_runtime.h>
#include <hip/hip_bf16.h>
#include <math.h>

#define LN 4
#define B_ 8
#define D_ 2048
#define DI 4096
#define N_ 128
#define H_ 64
#define P_ 64
#define K_ 4
#define M_ 8
#define V_ 50288
#define CCH (DI + 2*N_)           // 4352
#define DOUT (2*DI + 2*N_ + H_)   // 8512
#define EPSF 1e-5f
#define KT_IN 32                  // in_proj k-tiles (k0=64)
#define KT_OUT 128                // out_proj k-tiles (k0=32)

typedef float f32x4 __attribute__((ext_vector_type(4)));

__device__ inline float wave_sum(float v) {
  #pragma unroll
  for (int off = 32; off > 0; off >>= 1) v += __shfl_xor(v, off, 64);
  return v;
}

// Fold-reduce 8 per-lane accumulators: lane l gets full 64-lane sum of a[l&7].
__device__ inline float fold_reduce8(const float a[8], int lane) {
  float t0[4];
  #pragma unroll
  for (int r = 0; r < 4; ++r) {
    float keep = (lane & 1) ? a[2*r+1] : a[2*r];
    float send = (lane & 1) ? a[2*r]   : a[2*r+1];
    t0[r] = keep + __shfl_xor(send, 1, 64);
  }
  float t1[2];
  #pragma unroll
  for (int r = 0; r < 2; ++r) {
    float keep = (lane & 2) ? t0[2*r+1] : t0[2*r];
    float send = (lane & 2) ? t0[2*r]   : t0[2*r+1];
    t1[r] = keep + __shfl_xor(send, 2, 64);
  }
  float keep = (lane & 4) ? t1[1] : t1[0];
  float send = (lane & 4) ? t1[0] : t1[1];
  float u = keep + __shfl_xor(send, 4, 64);
  u += __shfl_xor(u, 8, 64);
  u += __shfl_xor(u, 16, 64);
  u += __shfl_xor(u, 32, 64);
  return u;
}

// ------- rmsnorm (one block per batch row), optional fused embed + res init
__global__ __launch_bounds__(256)
void k_rmsnorm(const float* __restrict__ in, const float* __restrict__ w,
               float* __restrict__ out, const int* __restrict__ ids,
               const float* __restrict__ emb, float* __restrict__ res_out) {
  __shared__ float lds[4];
  int b = blockIdx.x, tid = threadIdx.x;
  const float* row = ids ? (emb + (size_t)ids[b] * D_) : (in + (size_t)b * D_);
  f32x4 v0 = *reinterpret_cast<const f32x4*>(row + tid * 8);
  f32x4 v1 = *reinterpret_cast<const f32x4*>(row + tid * 8 + 4);
  if (res_out) {
    *reinterpret_cast<f32x4*>(res_out + (size_t)b * D_ + tid * 8)     = v0;
    *reinterpret_cast<f32x4*>(res_out + (size_t)b * D_ + tid * 8 + 4) = v1;
  }
  float ss = v0[0]*v0[0] + v0[1]*v0[1] + v0[2]*v0[2] + v0[3]*v0[3]
           + v1[0]*v1[0] + v1[1]*v1[1] + v1[2]*v1[2] + v1[3]*v1[3];
  float wsum = wave_sum(ss);
  int lane = tid & 63, wid = tid >> 6;
  if (lane == 0) lds[wid] = wsum;
  __syncthreads();
  float tot = lds[0] + lds[1] + lds[2] + lds[3];
  float scale = rsqrtf(tot / (float)D_ + EPSF);
  f32x4 w0 = *reinterpret_cast<const f32x4*>(w + tid * 8);
  f32x4 w1 = *reinterpret_cast<const f32x4*>(w + tid * 8 + 4);
  f32x4 o0 = v0 * scale * w0, o1 = v1 * scale * w1;
  *reinterpret_cast<f32x4*>(out + (size_t)b * D_ + tid * 8)     = o0;
  *reinterpret_cast<f32x4*>(out + (size_t)b * D_ + tid * 8 + 4) = o1;
}

// ---------------- in_proj stage 1: partials, NO atomics ----------------------
// grid = 9 j-tiles * 32 k-tiles = 288 blocks; pin[kt][r][j]
__global__ void k_inproj1(const float* __restrict__ xn, const float* __restrict__ W,
                          float* __restrict__ pin) {
  __shared__ float xs[8][64];
  int jt = blockIdx.x % 9, kt = blockIdx.x / 9;
  int k0 = kt * 64;
  for (int i = threadIdx.x; i < 8 * 64; i += 256) {
    int r = i >> 6, kk = i & 63;
    xs[r][kk] = xn[r * D_ + k0 + kk];
  }
  __syncthreads();
  int j = jt * 1024 + threadIdx.x * 4;
  if (j >= DOUT) return;
  f32x4 acc[8];
  #pragma unroll
  for (int r = 0; r < 8; ++r) acc[r] = (f32x4)0.f;
  const float* Wp = W + (size_t)k0 * DOUT + j;
  for (int kk = 0; kk < 64; ++kk) {
    f32x4 w4 = __builtin_nontemporal_load(
        reinterpret_cast<const f32x4*>(Wp + (size_t)kk * DOUT));
    #pragma unroll
    for (int r = 0; r < 8; ++r) acc[r] += w4 * xs[r][kk];
  }
  #pragma unroll
  for (int r = 0; r < 8; ++r)
    *reinterpret_cast<f32x4*>(&pin[((size_t)kt * 8 + r) * DOUT + j]) = acc[r];
}

// ------- in_proj stage 2: reduce partials -> zx, fused conv+dt+softmax -------
// 17024 threads (one f32x4 of the (b, DOUT) plane each), 67 blocks.
__global__ __launch_bounds__(256)
void k_inproj2_conv(const float* __restrict__ pin, const float* __restrict__ conv_state,
                    const float* __restrict__ conv_w, const float* __restrict__ conv_b,
                    const float* __restrict__ A_log, const float* __restrict__ dt_bias,
                    const float* __restrict__ W_mc,
                    float* __restrict__ zx, float* __restrict__ xbc,
                    float* __restrict__ dts, float* __restrict__ dav,
                    float* __restrict__ wmc) {
  const int TOT4 = B_ * DOUT / 4;   // 17024
  int t = blockIdx.x * 256 + threadIdx.x;
  if (t >= TOT4) return;
  f32x4 s = (f32x4)0.f;
  const f32x4* p4 = reinterpret_cast<const f32x4*>(pin) + t;
  #pragma unroll 8
  for (int kt = 0; kt < KT_IN; ++kt) s += p4[(size_t)kt * TOT4];
  reinterpret_cast<f32x4*>(zx)[t] = s;
  int c4 = t * 4;
  int b = c4 / DOUT;
  int c = c4 - b * DOUT;
  #pragma unroll
  for (int e = 0; e < 4; ++e) {
    int ce = c + e;
    if (ce >= DI && ce < DI + CCH) {
      int cc = ce - DI;
      f32x4 cs4 = *reinterpret_cast<const f32x4*>(conv_state + ((size_t)b * CCH + cc) * K_);
      f32x4 cw4 = *reinterpret_cast<const f32x4*>(conv_w + (size_t)cc * K_);
      float v = cs4[1] * cw4[0] + cs4[2] * cw4[1] + cs4[3] * cw4[2]
              + s[e] * cw4[3] + conv_b[cc];
      xbc[b * CCH + cc] = v / (1.f + expf(-v));   // silu
    } else if (ce >= DI + CCH) {
      int h = ce - DI - CCH;
      float x = s[e] + dt_bias[h];
      float sp = (x > 20.f) ? x : log1pf(expf(x));  // softplus
      dts[b * 64 + h] = sp;
      dav[b * 64 + h] = expf(-expf(A_log[h]) * sp);
    }
  }
  if (t == 0) {
    float mx = -1e30f;
    for (int i = 0; i < M_ + 1; ++i) mx = fmaxf(mx, W_mc[i]);
    float e2[M_ + 1], sum = 0.f;
    for (int i = 0; i < M_ + 1; ++i) { e2[i] = expf(W_mc[i] - mx); sum += e2[i]; }
    for (int i = 0; i < M_ + 1; ++i) wmc[i] = e2[i] / sum;
  }
}

// ---------------- state update + MC fuse + y (unchanged from R5) -------------
__global__ __launch_bounds__(256)
void k_state(const float* __restrict__ xbc, const float* __restrict__ dts,
             const float* __restrict__ dav, const float* __restrict__ Dp_,
             const float* __restrict__ wmc, const float* __restrict__ ssm,
             const float* __restrict__ cached, float* __restrict__ y) {
  int wg = blockIdx.x * 4 + (threadIdx.x >> 6);   // [0, 16384)
  int lane = threadIdx.x & 63;
  int b = wg >> 11;
  int h = (wg >> 5) & 63;
  int pp = wg & 31;
  int hf = lane >> 5, il = lane & 31;
  int p = pp * 2 + hf;
  float xv  = xbc[b * CCH + h * 64 + p];
  float dtv = dts[b * 64 + h];
  float da  = dav[b * 64 + h];
  float w8  = wmc[8];
  const f32x4* xb4 = reinterpret_cast<const f32x4*>(xbc);
  f32x4 B4 = xb4[b * (CCH / 4) + DI / 4 + il];
  f32x4 C4 = xb4[b * (CCH / 4) + DI / 4 + N_ / 4 + il];
  const f32x4* sp4 = reinterpret_cast<const f32x4*>(ssm) +
                     ((size_t)((b * H_ + h) * P_ + p)) * (N_ / 4) + il;
  const f32x4* cp4 = reinterpret_cast<const f32x4*>(cached) +
                     ((size_t)(((b * M_) * H_ + h) * P_ + p)) * (N_ / 4) + il;
  f32x4 s4 = __builtin_nontemporal_load(sp4);
  f32x4 f4 = (s4 * da + B4 * (dtv * xv)) * w8;
  #pragma unroll
  for (int m = 0; m < 8; ++m) {
    f32x4 c4 = __builtin_nontemporal_load(cp4 + (size_t)m * (H_ * P_ * N_ / 4));
    f4 += c4 * wmc[m];
  }
  f4 *= C4;
  float acc = f4[0] + f4[1] + f4[2] + f4[3];
  #pragma unroll
  for (int off = 1; off < 32; off <<= 1) acc += __shfl_xor(acc, off, 64);
  if (il == 0) y[b * DI + h * 64 + p] = acc + Dp_[h] * xv;
}

// ---------------- gated RMS norm: y*silu(z) then rms over 4096 ---------------
__global__ void k_gatednorm(const float* __restrict__ y, const float* __restrict__ zx,
                            const float* __restrict__ mnw, float* __restrict__ yg) {
  __shared__ float lds[8];
  int b = blockIdx.x;
  float tv[16];
  float ss = 0.f;
  #pragma unroll
  for (int t = 0; t < 16; ++t) {
    int i = threadIdx.x + t * 256;
    float z = zx[b * DOUT + i];
    float v = y[b * DI + i] * (z / (1.f + expf(-z)));
    tv[t] = v; ss += v * v;
  }
  float wsum = wave_sum(ss);
  int lane = threadIdx.x & 63, wid = threadIdx.x >> 6;
  if (lane == 0) lds[wid] = wsum;
  __syncthreads();
  float tot = lds[0] + lds[1] + lds[2] + lds[3];
  float scale = rsqrtf(tot / (float)DI + EPSF);
  #pragma unroll
  for (int t = 0; t < 16; ++t) {
    int i = threadIdx.x + t * 256;
    yg[b * DI + i] = tv[t] * scale * mnw[i];
  }
}

// ---------------- out_proj stage 1: partials, NO atomics ---------------------
// grid = 2 j-tiles * 128 k-tiles = 256 blocks; pout[kt][r][j]
__global__ void k_outproj1(const float* __restrict__ yg, const float* __restrict__ W,
                           float* __restrict__ pout) {
  __shared__ float xs[8][32];
  int jt = blockIdx.x & 1, kt = blockIdx.x >> 1;
  int k0 = kt * 32;
  for (int i = threadIdx.x; i < 8 * 32; i += 256) {
    int r = i >> 5, kk = i & 31;
    xs[r][kk] = yg[r * DI + k0 + kk];
  }
  __syncthreads();
  int j = jt * 1024 + threadIdx.x * 4;
  f32x4 acc[8];
  #pragma unroll
  for (int r = 0; r < 8; ++r) acc[r] = (f32x4)0.f;
  const float* Wp = W + (size_t)k0 * D_ + j;
  for (int kk = 0; kk < 32; ++kk) {
    f32x4 w4 = __builtin_nontemporal_load(
        reinterpret_cast<const f32x4*>(Wp + (size_t)kk * D_));
    #pragma unroll
    for (int r = 0; r < 8; ++r) acc[r] += w4 * xs[r][kk];
  }
  #pragma unroll
  for (int r = 0; r < 8; ++r)
    *reinterpret_cast<f32x4*>(&pout[((size_t)kt * 8 + r) * D_ + j]) = acc[r];
}

// ------- out_proj stage 2: reduce partials, res += (unique owner, no atomics),
// ------- optionally zero logits output buffer
__global__ __launch_bounds__(256)
void k_outproj2(const float* __restrict__ pout, float* __restrict__ res,
                float* __restrict__ zbuf, int zn4) {
  if (zbuf) {
    f32x4* z4 = reinterpret_cast<f32x4*>(zbuf);
    for (int i = blockIdx.x * 256 + threadIdx.x; i < zn4; i += 16 * 256)
      z4[i] = (f32x4)0.f;
  }
  const int TOT4 = B_ * D_ / 4;   // 4096
  int t = blockIdx.x * 256 + threadIdx.x;
  f32x4 s = (f32x4)0.f;
  const f32x4* p4 = reinterpret_cast<const f32x4*>(pout) + t;
  #pragma unroll 8
  for (int kt = 0; kt < KT_OUT; ++kt) s += p4[(size_t)kt * TOT4];
  reinterpret_cast<f32x4*>(res)[t] += s;
}

// ---------------- logits: wave-per-row, split-D (SL=4) — R5-proven shape -----
#define SL_ 4
#define KS_ (D_ / SL_)            // 512
#define NVB16 (V_ / 16)           // 3143 (exact)
__global__ __launch_bounds__(256)
void k_logits(const float* __restrict__ xn, const float* __restrict__ emb,
              float* __restrict__ out) {
  __shared__ f32x4 xs[8][KS_ / 4];   // 16 KB -> 8 blocks/CU, 32 waves/CU
  int s = blockIdx.x & 3, vb = blockIdx.x >> 2;
  const f32x4* xn4 = reinterpret_cast<const f32x4*>(xn);
  for (int i = threadIdx.x; i < 8 * (KS_ / 4); i += 256) {
    int r = i >> 7, q = i & 127;
    xs[r][q] = xn4[r * (D_ / 4) + s * (KS_ / 4) + q];
  }
  __syncthreads();
  int wid = threadIdx.x >> 6, lane = threadIdx.x & 63;
  int v0 = vb * 16 + wid * 4;
  const f32x4* e4 = reinterpret_cast<const f32x4*>(emb);
  #pragma unroll
  for (int vv = 0; vv < 4; ++vv) {
    int v = v0 + vv;
    const f32x4* ep = e4 + (size_t)v * (D_ / 4) + s * (KS_ / 4);
    float acc[8] = {0,0,0,0,0,0,0,0};
    #pragma unroll
    for (int st = 0; st < KS_ / 256; ++st) {
      int c = st * 64 + lane;
      f32x4 e = __builtin_nontemporal_load(ep + c);
      #pragma unroll
      for (int r = 0; r < 8; ++r) {
        f32x4 x = xs[r][c];
        acc[r] += e[0]*x[0] + e[1]*x[1] + e[2]*x[2] + e[3]*x[3];
      }
    }
    float u = fold_reduce8(acc, lane);
    if (lane < 8) atomicAdd(&out[(size_t)lane * V_ + v], u);
  }
}

extern "C" void kernel_launch(void* const* d_in, const int* in_sizes, int n_in,
                              void* d_out, int out_size, void* d_ws, size_t ws_size,
                              hipStream_t stream) {
  const int*   ids    = (const int*)  d_in[0];
  const float* emb    = (const float*)d_in[1];
  const float* inW    = (const float*)d_in[2];
  const float* convW  = (const float*)d_in[3];
  const float* convB  = (const float*)d_in[4];
  const float* Alog   = (const float*)d_in[5];
  const float* dtB    = (const float*)d_in[6];
  const float* Dpar   = (const float*)d_in[7];
  const float* mnw    = (const float*)d_in[8];
  const float* outW   = (const float*)d_in[9];
  const float* lnw    = (const float*)d_in[10];
  const float* nfw    = (const float*)d_in[11];
  const float* Wmc    = (const float*)d_in[12];
  const float* convS  = (const float*)d_in[13];
  const float* ssmS   = (const float*)d_in[14];
  const float* cached = (const float*)d_in[15];
  float* out = (float*)d_out;
  float* ws  = (float*)d_ws;

  float* res  = ws;            // 16384 floats
  float* xn   = ws + 16384;    // 16384
  float* zx   = ws + 32768;    // 68096
  float* xbc  = ws + 100864;   // 34816
  float* dts  = ws + 135680;   // 512
  float* dav  = ws + 136192;   // 512
  float* wmc  = ws + 136704;   // 64
  float* y    = ws + 136768;   // 32768
  float* yg   = ws + 169536;   // 32768
  float* pin  = ws + 202304;   // 32*8*8512 = 2179072
  float* pout = ws + 2381376;  // 128*8*2048 = 2097152 -> ends 4478528 (~17.9MB)

  for (int l = 0; l < LN; ++l) {
    if (l == 0)
      k_rmsnorm<<<8, 256, 0, stream>>>(nullptr, lnw, xn, ids, emb, res);
    else
      k_rmsnorm<<<8, 256, 0, stream>>>(res, lnw + (size_t)l * D_, xn,
                                       nullptr, nullptr, nullptr);
    k_inproj1<<<288, 256, 0, stream>>>(xn, inW + (size_t)l * D_ * DOUT, pin);
    k_inproj2_conv<<<67, 256, 0, stream>>>(pin,
        convS + (size_t)l * B_ * CCH * K_, convW + (size_t)l * CCH * K_,
        convB + (size_t)l * CCH, Alog + l * H_, dtB + l * H_, Wmc + l * (M_ + 1),
        zx, xbc, dts, dav, wmc);
    k_state<<<4096, 256, 0, stream>>>(xbc, dts, dav, Dpar + l * H_, wmc,
        ssmS + (size_t)l * B_ * H_ * P_ * N_,
        cached + (size_t)l * B_ * M_ * H_ * P_ * N_, y);
    k_gatednorm<<<8, 256, 0, stream>>>(y, zx, mnw + (size_t)l * DI, yg);
    k_outproj1<<<256, 256, 0, stream>>>(yg, outW + (size_t)l * DI * D_, pout);
    k_outproj2<<<16, 256, 0, stream>>>(pout, res,
                                       (l == LN - 1) ? out : nullptr,
                                       B_ * V_ / 4);
  }
  k_rmsnorm<<<8, 256, 0, stream>>>(res, nfw, xn, nullptr, nullptr, nullptr);
  k_logits<<<NVB16 * SL_, 256, 0, stream>>>(xn, emb, out);
}

// Round 8
// 435.462 us; speedup vs baseline: 1.6221x; 1.0969x over previous
//
#include <hip/hip_runtime.h>
#include <hip/hip_bf16.h>
#include <math.h>

#define LN 4
#define B_ 8
#define D_ 2048
#define DI 4096
#define N_ 128
#define H_ 64
#define P_ 64
#define K_ 4
#define M_ 8
#define V_ 50288
#define CCH (DI + 2*N_)           // 4352
#define DOUT (2*DI + 2*N_ + H_)   // 8512
#define EPSF 1e-5f
#define KT_IN 32                  // in_proj k-tiles (k0=64)
#define KT_OUT 128                // out_proj k-tiles (k0=32)

typedef float f32x4 __attribute__((ext_vector_type(4)));

__device__ inline float wave_sum(float v) {
  #pragma unroll
  for (int off = 32; off > 0; off >>= 1) v += __shfl_xor(v, off, 64);
  return v;
}

// Fold-reduce 8 per-lane accumulators: lane l gets full 64-lane sum of a[l&7].
__device__ inline float fold_reduce8(const float a[8], int lane) {
  float t0[4];
  #pragma unroll
  for (int r = 0; r < 4; ++r) {
    float keep = (lane & 1) ? a[2*r+1] : a[2*r];
    float send = (lane & 1) ? a[2*r]   : a[2*r+1];
    t0[r] = keep + __shfl_xor(send, 1, 64);
  }
  float t1[2];
  #pragma unroll
  for (int r = 0; r < 2; ++r) {
    float keep = (lane & 2) ? t0[2*r+1] : t0[2*r];
    float send = (lane & 2) ? t0[2*r]   : t0[2*r+1];
    t1[r] = keep + __shfl_xor(send, 2, 64);
  }
  float keep = (lane & 4) ? t1[1] : t1[0];
  float send = (lane & 4) ? t1[0] : t1[1];
  float u = keep + __shfl_xor(send, 4, 64);
  u += __shfl_xor(u, 8, 64);
  u += __shfl_xor(u, 16, 64);
  u += __shfl_xor(u, 32, 64);
  return u;
}

// ------- final rmsnorm (one block per batch row) — feeds logits only ---------
__global__ __launch_bounds__(256)
void k_rmsnorm(const float* __restrict__ in, const float* __restrict__ w,
               float* __restrict__ out) {
  __shared__ float lds[4];
  int b = blockIdx.x, tid = threadIdx.x;
  const float* row = in + (size_t)b * D_;
  f32x4 v0 = *reinterpret_cast<const f32x4*>(row + tid * 8);
  f32x4 v1 = *reinterpret_cast<const f32x4*>(row + tid * 8 + 4);
  float ss = v0[0]*v0[0] + v0[1]*v0[1] + v0[2]*v0[2] + v0[3]*v0[3]
           + v1[0]*v1[0] + v1[1]*v1[1] + v1[2]*v1[2] + v1[3]*v1[3];
  float wsum = wave_sum(ss);
  int lane = tid & 63, wid = tid >> 6;
  if (lane == 0) lds[wid] = wsum;
  __syncthreads();
  float tot = lds[0] + lds[1] + lds[2] + lds[3];
  float scale = rsqrtf(tot / (float)D_ + EPSF);
  f32x4 w0 = *reinterpret_cast<const f32x4*>(w + tid * 8);
  f32x4 w1 = *reinterpret_cast<const f32x4*>(w + tid * 8 + 4);
  f32x4 o0 = v0 * scale * w0, o1 = v1 * scale * w1;
  *reinterpret_cast<f32x4*>(out + (size_t)b * D_ + tid * 8)     = o0;
  *reinterpret_cast<f32x4*>(out + (size_t)b * D_ + tid * 8 + 4) = o1;
}

// ------ in_proj stage 1 with FUSED rmsnorm: partials, no atomics -------------
// grid = 9 j-tiles * 32 k-tiles = 288 blocks; pin[kt][r][j].
// Each block redundantly computes the 8 row-norms from res (64KB, L2-hot),
// then stages xs[r][kk] = src*scale*lnw. L0 (ids!=null) gathers emb[ids[b]].
__global__ __launch_bounds__(256)
void k_inproj1(const float* __restrict__ res, const int* __restrict__ ids,
               const float* __restrict__ emb, const float* __restrict__ lnw,
               const float* __restrict__ W, float* __restrict__ pin) {
  __shared__ float xs[8][64];
  __shared__ float sred[4][8];
  int tid = threadIdx.x, lane = tid & 63, wid = tid >> 6;
  int jt = blockIdx.x % 9, kt = blockIdx.x / 9;
  int k0 = kt * 64;
  // --- row sum-of-squares (each thread: 8 floats per row) ---
  float ssq[8];
  #pragma unroll
  for (int r = 0; r < 8; ++r) {
    const float* row = ids ? (emb + (size_t)ids[r] * D_) : (res + (size_t)r * D_);
    f32x4 a = *reinterpret_cast<const f32x4*>(row + tid * 8);
    f32x4 c = *reinterpret_cast<const f32x4*>(row + tid * 8 + 4);
    ssq[r] = a[0]*a[0] + a[1]*a[1] + a[2]*a[2] + a[3]*a[3]
           + c[0]*c[0] + c[1]*c[1] + c[2]*c[2] + c[3]*c[3];
  }
  #pragma unroll
  for (int r = 0; r < 8; ++r) {
    float wsum = wave_sum(ssq[r]);
    if (lane == 0) sred[wid][r] = wsum;
  }
  __syncthreads();
  // --- stage normalized slice ---
  for (int i = tid; i < 8 * 64; i += 256) {
    int r = i >> 6, kk = i & 63;
    const float* row = ids ? (emb + (size_t)ids[r] * D_) : (res + (size_t)r * D_);
    float tot = sred[0][r] + sred[1][r] + sred[2][r] + sred[3][r];
    float scale = rsqrtf(tot / (float)D_ + EPSF);
    xs[r][kk] = row[k0 + kk] * scale * lnw[k0 + kk];
  }
  __syncthreads();
  int j = jt * 1024 + tid * 4;
  if (j >= DOUT) return;
  f32x4 acc[8];
  #pragma unroll
  for (int r = 0; r < 8; ++r) acc[r] = (f32x4)0.f;
  const float* Wp = W + (size_t)k0 * DOUT + j;
  for (int kk = 0; kk < 64; ++kk) {
    f32x4 w4 = __builtin_nontemporal_load(
        reinterpret_cast<const f32x4*>(Wp + (size_t)kk * DOUT));
    #pragma unroll
    for (int r = 0; r < 8; ++r) acc[r] += w4 * xs[r][kk];
  }
  #pragma unroll
  for (int r = 0; r < 8; ++r)
    *reinterpret_cast<f32x4*>(&pin[((size_t)kt * 8 + r) * DOUT + j]) = acc[r];
}

// ------- in_proj stage 2: reduce partials -> zx, fused conv+dt+softmax -------
__global__ __launch_bounds__(256)
void k_inproj2_conv(const float* __restrict__ pin, const float* __restrict__ conv_state,
                    const float* __restrict__ conv_w, const float* __restrict__ conv_b,
                    const float* __restrict__ A_log, const float* __restrict__ dt_bias,
                    const float* __restrict__ W_mc,
                    float* __restrict__ zx, float* __restrict__ xbc,
                    float* __restrict__ dts, float* __restrict__ dav,
                    float* __restrict__ wmc) {
  const int TOT4 = B_ * DOUT / 4;   // 17024
  int t = blockIdx.x * 256 + threadIdx.x;
  if (t >= TOT4) return;
  f32x4 s = (f32x4)0.f;
  const f32x4* p4 = reinterpret_cast<const f32x4*>(pin) + t;
  #pragma unroll 8
  for (int kt = 0; kt < KT_IN; ++kt) s += p4[(size_t)kt * TOT4];
  reinterpret_cast<f32x4*>(zx)[t] = s;
  int c4 = t * 4;
  int b = c4 / DOUT;
  int c = c4 - b * DOUT;
  #pragma unroll
  for (int e = 0; e < 4; ++e) {
    int ce = c + e;
    if (ce >= DI && ce < DI + CCH) {
      int cc = ce - DI;
      f32x4 cs4 = *reinterpret_cast<const f32x4*>(conv_state + ((size_t)b * CCH + cc) * K_);
      f32x4 cw4 = *reinterpret_cast<const f32x4*>(conv_w + (size_t)cc * K_);
      float v = cs4[1] * cw4[0] + cs4[2] * cw4[1] + cs4[3] * cw4[2]
              + s[e] * cw4[3] + conv_b[cc];
      xbc[b * CCH + cc] = v / (1.f + expf(-v));   // silu
    } else if (ce >= DI + CCH) {
      int h = ce - DI - CCH;
      float x = s[e] + dt_bias[h];
      float sp = (x > 20.f) ? x : log1pf(expf(x));  // softplus
      dts[b * 64 + h] = sp;
      dav[b * 64 + h] = expf(-expf(A_log[h]) * sp);
    }
  }
  if (t == 0) {
    float mx = -1e30f;
    for (int i = 0; i < M_ + 1; ++i) mx = fmaxf(mx, W_mc[i]);
    float e2[M_ + 1], sum = 0.f;
    for (int i = 0; i < M_ + 1; ++i) { e2[i] = expf(W_mc[i] - mx); sum += e2[i]; }
    for (int i = 0; i < M_ + 1; ++i) wmc[i] = e2[i] / sum;
  }
}

// ---------------- state update + MC fuse + y ---------------------------------
__global__ __launch_bounds__(256)
void k_state(const float* __restrict__ xbc, const float* __restrict__ dts,
             const float* __restrict__ dav, const float* __restrict__ Dp_,
             const float* __restrict__ wmc, const float* __restrict__ ssm,
             const float* __restrict__ cached, float* __restrict__ y) {
  int wg = blockIdx.x * 4 + (threadIdx.x >> 6);   // [0, 16384)
  int lane = threadIdx.x & 63;
  int b = wg >> 11;
  int h = (wg >> 5) & 63;
  int pp = wg & 31;
  int hf = lane >> 5, il = lane & 31;
  int p = pp * 2 + hf;
  float xv  = xbc[b * CCH + h * 64 + p];
  float dtv = dts[b * 64 + h];
  float da  = dav[b * 64 + h];
  float w8  = wmc[8];
  const f32x4* xb4 = reinterpret_cast<const f32x4*>(xbc);
  f32x4 B4 = xb4[b * (CCH / 4) + DI / 4 + il];
  f32x4 C4 = xb4[b * (CCH / 4) + DI / 4 + N_ / 4 + il];
  const f32x4* sp4 = reinterpret_cast<const f32x4*>(ssm) +
                     ((size_t)((b * H_ + h) * P_ + p)) * (N_ / 4) + il;
  const f32x4* cp4 = reinterpret_cast<const f32x4*>(cached) +
                     ((size_t)(((b * M_) * H_ + h) * P_ + p)) * (N_ / 4) + il;
  f32x4 s4 = __builtin_nontemporal_load(sp4);
  f32x4 f4 = (s4 * da + B4 * (dtv * xv)) * w8;
  #pragma unroll
  for (int m = 0; m < 8; ++m) {
    f32x4 c4 = __builtin_nontemporal_load(cp4 + (size_t)m * (H_ * P_ * N_ / 4));
    f4 += c4 * wmc[m];
  }
  f4 *= C4;
  float acc = f4[0] + f4[1] + f4[2] + f4[3];
  #pragma unroll
  for (int off = 1; off < 32; off <<= 1) acc += __shfl_xor(acc, off, 64);
  if (il == 0) y[b * DI + h * 64 + p] = acc + Dp_[h] * xv;
}

// ---------------- gated RMS norm: y*silu(z) then rms over 4096 ---------------
__global__ void k_gatednorm(const float* __restrict__ y, const float* __restrict__ zx,
                            const float* __restrict__ mnw, float* __restrict__ yg) {
  __shared__ float lds[8];
  int b = blockIdx.x;
  float tv[16];
  float ss = 0.f;
  #pragma unroll
  for (int t = 0; t < 16; ++t) {
    int i = threadIdx.x + t * 256;
    float z = zx[b * DOUT + i];
    float v = y[b * DI + i] * (z / (1.f + expf(-z)));
    tv[t] = v; ss += v * v;
  }
  float wsum = wave_sum(ss);
  int lane = threadIdx.x & 63, wid = threadIdx.x >> 6;
  if (lane == 0) lds[wid] = wsum;
  __syncthreads();
  float tot = lds[0] + lds[1] + lds[2] + lds[3];
  float scale = rsqrtf(tot / (float)DI + EPSF);
  #pragma unroll
  for (int t = 0; t < 16; ++t) {
    int i = threadIdx.x + t * 256;
    yg[b * DI + i] = tv[t] * scale * mnw[i];
  }
}

// ---------------- out_proj stage 1: partials, NO atomics ---------------------
__global__ void k_outproj1(const float* __restrict__ yg, const float* __restrict__ W,
                           float* __restrict__ pout) {
  __shared__ float xs[8][32];
  int jt = blockIdx.x & 1, kt = blockIdx.x >> 1;
  int k0 = kt * 32;
  for (int i = threadIdx.x; i < 8 * 32; i += 256) {
    int r = i >> 5, kk = i & 31;
    xs[r][kk] = yg[r * DI + k0 + kk];
  }
  __syncthreads();
  int j = jt * 1024 + threadIdx.x * 4;
  f32x4 acc[8];
  #pragma unroll
  for (int r = 0; r < 8; ++r) acc[r] = (f32x4)0.f;
  const float* Wp = W + (size_t)k0 * D_ + j;
  for (int kk = 0; kk < 32; ++kk) {
    f32x4 w4 = __builtin_nontemporal_load(
        reinterpret_cast<const f32x4*>(Wp + (size_t)kk * D_));
    #pragma unroll
    for (int r = 0; r < 8; ++r) acc[r] += w4 * xs[r][kk];
  }
  #pragma unroll
  for (int r = 0; r < 8; ++r)
    *reinterpret_cast<f32x4*>(&pout[((size_t)kt * 8 + r) * D_ + j]) = acc[r];
}

// ------- out_proj stage 2: 64 blocks, wave-per-kt-quarter, LDS combine -------
// res += reduced partials (single writer). L0 (ids!=null): res = emb[ids] + sum.
__global__ __launch_bounds__(256)
void k_outproj2(const float* __restrict__ pout, float* __restrict__ res,
                const int* __restrict__ ids, const float* __restrict__ emb) {
  __shared__ f32x4 red[256];
  const int TOT4 = B_ * D_ / 4;   // 4096
  int tid = threadIdx.x;
  int pos = blockIdx.x * 64 + (tid & 63);
  int kq = tid >> 6;              // wave index = kt quarter
  const f32x4* p4 = reinterpret_cast<const f32x4*>(pout) + pos;
  f32x4 s = (f32x4)0.f;
  #pragma unroll 8
  for (int k = 0; k < 32; ++k)
    s += p4[(size_t)(kq * 32 + k) * TOT4];
  red[tid] = s;
  __syncthreads();
  if (tid < 64) {
    f32x4 tot = red[tid] + red[tid + 64] + red[tid + 128] + red[tid + 192];
    f32x4* r4 = reinterpret_cast<f32x4*>(res);
    if (ids) {
      int b = pos >> 9, d4 = pos & 511;
      f32x4 base = reinterpret_cast<const f32x4*>(emb)[(size_t)ids[b] * (D_ / 4) + d4];
      r4[pos] = base + tot;
    } else {
      r4[pos] += tot;
    }
  }
}

// ---------------- logits: wave-per-row, split-D (SL=4), partial stores -------
#define SL_ 4
#define KS_ (D_ / SL_)            // 512
#define NVB16 (V_ / 16)           // 3143 (exact)
__global__ __launch_bounds__(256)
void k_logits(const float* __restrict__ xn, const float* __restrict__ emb,
              float* __restrict__ pl) {
  __shared__ f32x4 xs[8][KS_ / 4];   // 16 KB -> 8 blocks/CU, 32 waves/CU
  int s = blockIdx.x & 3, vb = blockIdx.x >> 2;
  const f32x4* xn4 = reinterpret_cast<const f32x4*>(xn);
  for (int i = threadIdx.x; i < 8 * (KS_ / 4); i += 256) {
    int r = i >> 7, q = i & 127;
    xs[r][q] = xn4[r * (D_ / 4) + s * (KS_ / 4) + q];
  }
  __syncthreads();
  int wid = threadIdx.x >> 6, lane = threadIdx.x & 63;
  int v0 = vb * 16 + wid * 4;
  const f32x4* e4 = reinterpret_cast<const f32x4*>(emb);
  #pragma unroll
  for (int vv = 0; vv < 4; ++vv) {
    int v = v0 + vv;
    const f32x4* ep = e4 + (size_t)v * (D_ / 4) + s * (KS_ / 4);
    float acc[8] = {0,0,0,0,0,0,0,0};
    #pragma unroll
    for (int st = 0; st < KS_ / 256; ++st) {
      int c = st * 64 + lane;
      f32x4 e = __builtin_nontemporal_load(ep + c);
      #pragma unroll
      for (int r = 0; r < 8; ++r) {
        f32x4 x = xs[r][c];
        acc[r] += e[0]*x[0] + e[1]*x[1] + e[2]*x[2] + e[3]*x[3];
      }
    }
    float u = fold_reduce8(acc, lane);
    if (lane < 8) pl[((size_t)s * 8 + lane) * V_ + v] = u;
  }
}

// ---------------- logits combine: out = sum of 4 slice partials --------------
__global__ __launch_bounds__(256)
void k_logits2(const float* __restrict__ pl, float* __restrict__ out) {
  int v = blockIdx.x * 256 + threadIdx.x;
  if (v >= V_) return;
  int r = blockIdx.y;
  float t = pl[(size_t)r * V_ + v]
          + pl[((size_t)8  + r) * V_ + v]
          + pl[((size_t)16 + r) * V_ + v]
          + pl[((size_t)24 + r) * V_ + v];
  out[(size_t)r * V_ + v] = t;
}

extern "C" void kernel_launch(void* const* d_in, const int* in_sizes, int n_in,
                              void* d_out, int out_size, void* d_ws, size_t ws_size,
                              hipStream_t stream) {
  const int*   ids    = (const int*)  d_in[0];
  const float* emb    = (const float*)d_in[1];
  const float* inW    = (const float*)d_in[2];
  const float* convW  = (const float*)d_in[3];
  const float* convB  = (const float*)d_in[4];
  const float* Alog   = (const float*)d_in[5];
  const float* dtB    = (const float*)d_in[6];
  const float* Dpar   = (const float*)d_in[7];
  const float* mnw    = (const float*)d_in[8];
  const float* outW   = (const float*)d_in[9];
  const float* lnw    = (const float*)d_in[10];
  const float* nfw    = (const float*)d_in[11];
  const float* Wmc    = (const float*)d_in[12];
  const float* convS  = (const float*)d_in[13];
  const float* ssmS   = (const float*)d_in[14];
  const float* cached = (const float*)d_in[15];
  float* out = (float*)d_out;
  float* ws  = (float*)d_ws;

  float* res  = ws;            // 16384 floats
  float* xn   = ws + 16384;    // 16384
  float* zx   = ws + 32768;    // 68096
  float* xbc  = ws + 100864;   // 34816
  float* dts  = ws + 135680;   // 512
  float* dav  = ws + 136192;   // 512
  float* wmc  = ws + 136704;   // 64
  float* y    = ws + 136768;   // 32768
  float* yg   = ws + 169536;   // 32768
  float* pin  = ws + 202304;   // 32*8*8512 = 2179072
  float* pout = ws + 2381376;  // 128*8*2048 = 2097152
  float* pl   = ws + 4478528;  // 4*8*50288 = 1609216 -> ends 6087744 (~24.4MB)

  for (int l = 0; l < LN; ++l) {
    k_inproj1<<<288, 256, 0, stream>>>(res, (l == 0) ? ids : nullptr, emb,
                                       lnw + (size_t)l * D_,
                                       inW + (size_t)l * D_ * DOUT, pin);
    k_inproj2_conv<<<67, 256, 0, stream>>>(pin,
        convS + (size_t)l * B_ * CCH * K_, convW + (size_t)l * CCH * K_,
        convB + (size_t)l * CCH, Alog + l * H_, dtB + l * H_, Wmc + l * (M_ + 1),
        zx, xbc, dts, dav, wmc);
    k_state<<<4096, 256, 0, stream>>>(xbc, dts, dav, Dpar + l * H_, wmc,
        ssmS + (size_t)l * B_ * H_ * P_ * N_,
        cached + (size_t)l * B_ * M_ * H_ * P_ * N_, y);
    k_gatednorm<<<8, 256, 0, stream>>>(y, zx, mnw + (size_t)l * DI, yg);
    k_outproj1<<<256, 256, 0, stream>>>(yg, outW + (size_t)l * DI * D_, pout);
    k_outproj2<<<64, 256, 0, stream>>>(pout, res,
                                       (l == 0) ? ids : nullptr, emb);
  }
  k_rmsnorm<<<8, 256, 0, stream>>>(res, nfw, xn);
  k_logits<<<NVB16 * SL_, 256, 0, stream>>>(xn, emb, pl);
  k_logits2<<<dim3((V_ + 255) / 256, 8), 256, 0, stream>>>(pl, out);
}